// Round 6
// baseline (10385.547 us; speedup 1.0000x reference)
//
#include <hip/hip_runtime.h>
#include <hip/hip_bf16.h>
#include <stdint.h>

typedef __attribute__((ext_vector_type(8))) short short8;
typedef __attribute__((ext_vector_type(4))) float f32x4;
typedef __attribute__((ext_vector_type(4))) int int4v;

__device__ __forceinline__ float bf2f(unsigned short u) {
  union { unsigned int i; float f; } v; v.i = ((unsigned int)u) << 16; return v.f;
}
__device__ __forceinline__ unsigned short f2bf(float f) {
  union { float f; unsigned int i; } v; v.f = f;
  unsigned int i = v.i;
  i += 0x7FFFu + ((i >> 16) & 1u);
  return (unsigned short)(i >> 16);
}
__device__ __forceinline__ float tanh_fast(float x) {
  float e = __expf(2.0f * x);           // e=+inf -> 1; e->0 -> -1 (robust)
  return 1.0f - 2.0f / (e + 1.0f);
}

// ---------------- weight prep ----------------
// ODE: wimg[layer][arr(hi/lo)][icb][oc][tap][icm]  (bf16, 73728 elems/layer)
// s1wt[ky][kx][ic64][oc32], s2wt[ky][kx][ic32][oc16], s3wt[ky][kx][ic16]  (f32)
__global__ void prep_weights(const float* __restrict__ w1, const float* __restrict__ w2,
                             const float* __restrict__ w3, const float* __restrict__ w4,
                             const float* __restrict__ s1w, const float* __restrict__ s2w,
                             const float* __restrict__ s3w,
                             unsigned short* __restrict__ wimg,
                             float* __restrict__ s1wt, float* __restrict__ s2wt,
                             float* __restrict__ s3wt) {
  int t = blockIdx.x * 256 + threadIdx.x;
  if (t < 147456) {
    int l = t / 36864;
    int oc = (t / 576) & 63;
    int ic = (t / 9) & 63;
    int tap = t % 9;
    const float* w = (l == 0) ? w1 : (l == 1) ? w2 : (l == 2) ? w3 : w4;
    float v = w[(oc * 64 + ic) * 9 + tap];
    unsigned short hi = f2bf(v);
    unsigned short lo = f2bf(v - bf2f(hi));
    int icb = ic >> 5, icm = ic & 31;
    int idx = (icb * 64 + oc) * 288 + tap * 32 + icm;
    wimg[l * 73728 + idx]         = hi;
    wimg[l * 73728 + 36864 + idx] = lo;
  } else if (t < 180224) {
    int u = t - 147456;                       // ((ky*4+kx)*64+ic)*32+oc
    int oc = u & 31, ic = (u >> 5) & 63, kk = u >> 11;
    int ky = kk >> 2, kx = kk & 3;
    s1wt[u] = s1w[((oc * 64 + ic) * 4 + ky) * 4 + kx];
  } else if (t < 188416) {
    int u = t - 180224;                       // ((ky*4+kx)*32+ic)*16+oc
    int oc = u & 15, ic = (u >> 4) & 31, kk = u >> 9;
    int ky = kk >> 2, kx = kk & 3;
    s2wt[u] = s2w[((oc * 32 + ic) * 4 + ky) * 4 + kx];
  } else if (t < 188560) {
    int u = t - 188416;                       // (ky*3+kx)*16+ic
    int ic = u & 15, kk = u >> 4;
    int ky = kk / 3, kx = kk % 3;
    s3wt[u] = s3w[ic * 9 + ky * 3 + kx];
  }
}

// NCHW h_s0 -> NHWC bf16 pair (S0) + f32 outs[0]
__global__ void prep_state(const float* __restrict__ src,
                           unsigned short* __restrict__ s0h, unsigned short* __restrict__ s0l,
                           float* __restrict__ outs0) {
  int t = blockIdx.x * 256 + threadIdx.x;    // NHWC flat: ((b*32+h)*32+w)*64+c
  int c = t & 63, w = (t >> 6) & 31, h = (t >> 11) & 31, b = t >> 16;
  float v = src[((b * 64 + c) * 32 + h) * 32 + w];
  unsigned short hi = f2bf(v);
  s0h[t] = hi;
  s0l[t] = f2bf(v - bf2f(hi));
  outs0[t] = v;
}

// ---------------- ODE conv body: oc-split implicit GEMM, bf16 hi/lo, MFMA ------
// block = 256 thr (4 waves); block computes M=64 px (2 rows) x N=16 oc (group g)
// LDS: A [arr2][row4][w34][144B] = 39168 B ; W [(arr,icb)4][oc16][624B] = 39936 B
#define LDS_A_ARR 19584
#define LDS_W_BASE 39168
#define LDS_W_ARROFF 19968                   // arr=1 region offset (2 * 16 * 624)
#define CONV_LDS 79104

__device__ __forceinline__ void conv_body(
    uint8_t* lds, int b, int h0, int g,
    const unsigned short* __restrict__ inHi, const unsigned short* __restrict__ inLo,
    const unsigned short* __restrict__ wimg, const float* __restrict__ bias,
    unsigned short* __restrict__ outHi, unsigned short* __restrict__ outLo,
    const unsigned short* __restrict__ yHi, const unsigned short* __restrict__ yLo,
    float* __restrict__ accBuf, float* __restrict__ outsPtr, int mode) {
  const int tid = threadIdx.x;

  // ---- stage A-tile (rows h0-1..h0+2, width 0..33 padded, 8x16B ic-chunks, hi+lo)
  for (int idx = tid; idx < 2176; idx += 256) {
    int arr = idx / 1088;
    int r2 = idx - arr * 1088;
    int c = r2 & 7;
    int w1 = (r2 >> 3) % 34;
    int row = (r2 >> 3) / 34;
    int hp = h0 - 1 + row;
    int w = w1 - 1;
    int4v v = {0, 0, 0, 0};
    if (hp >= 0 && hp < 32 && w >= 0 && w < 32) {
      const unsigned short* sp = arr ? inLo : inHi;
      v = *(const int4v*)(sp + (((b * 32 + hp) * 32 + w) * 64 + c * 8));
    }
    *(int4v*)(lds + ((arr * 4 + row) * 34 + w1) * 144 + c * 16) = v;
  }
  // ---- stage W: this block's 16 oc, both icb, hi+lo. 2304 chunks = 9/thread.
#pragma unroll
  for (int k = 0; k < 9; ++k) {
    int c = tid + k * 256;                    // [arr2][icb2][oc16][ch36]
    int arr = c / 1152;
    int c2 = c - arr * 1152;
    int icb = c2 / 576;
    int c3 = c2 - icb * 576;
    int oc_l = c3 / 36;
    int ch = c3 - oc_l * 36;
    int4v v = *(const int4v*)(wimg + (((arr * 2 + icb) * 64 + g * 16 + oc_l) * 288 + ch * 8));
    *(int4v*)(lds + LDS_W_BASE + ((arr * 2 + icb) * 16 + oc_l) * 624 + ch * 16) = v;
  }
  __syncthreads();

  const int lane = tid & 63;
  const int wv = tid >> 6;
  const int lmod = lane & 15;
  const int lg = lane >> 4;
  const int P = wv * 16 + lmod;               // A-operand pixel (m = lane&15)
  const int r = P >> 5;                       // wave-uniform
  const int c0 = P & 31;

  f32x4 acc = (f32x4){0.f, 0.f, 0.f, 0.f};

#pragma unroll
  for (int icb = 0; icb < 2; ++icb) {
#pragma unroll
    for (int tap = 0; tap < 9; ++tap) {
      const int dy = tap / 3, dx = tap % 3;
      const int abyte = ((r + dy) * 34 + (c0 + dx)) * 144 + (icb * 4 + lg) * 16;
      short8 ah = *(const short8*)(lds + abyte);
      short8 al = *(const short8*)(lds + abyte + LDS_A_ARR);
      const int wb = LDS_W_BASE + (icb * 16 + lmod) * 624 + tap * 64 + lg * 16;
      short8 bh = *(const short8*)(lds + wb);
      short8 bl = *(const short8*)(lds + wb + LDS_W_ARROFF);
      acc = __builtin_amdgcn_mfma_f32_16x16x32_bf16(ah, bh, acc, 0, 0, 0);
      acc = __builtin_amdgcn_mfma_f32_16x16x32_bf16(al, bh, acc, 0, 0, 0);
      acc = __builtin_amdgcn_mfma_f32_16x16x32_bf16(ah, bl, acc, 0, 0, 0);
    }
  }

  // ---- epilogue: D[m=(lane>>4)*4+j][n=lane&15], oc = g*16 + n
  const int oc = g * 16 + lmod;
  const float bz = bias[oc];
#pragma unroll
  for (int j = 0; j < 4; ++j) {
    const int Pp = wv * 16 + lg * 4 + j;
    const int e = (b * 1024 + h0 * 32 + Pp) * 64 + oc;
    float kv = acc[j] + bz;
    if (mode == 0) {                          // conv + tanh -> pair
      float v = tanh_fast(kv);
      unsigned short hi = f2bf(v);
      outHi[e] = hi;
      outLo[e] = f2bf(v - bf2f(hi));
    } else if (mode == 1) {                   // k1: z=y+0.25k ; ACC=y+k/12
      float y = bf2f(yHi[e]) + bf2f(yLo[e]);
      float z = fmaf(0.25f, kv, y);
      accBuf[e] = fmaf(1.0f / 12.0f, kv, y);
      unsigned short hi = f2bf(z);
      outHi[e] = hi;
      outLo[e] = f2bf(z - bf2f(hi));
    } else if (mode == 2 || mode == 3) {      // k2/k3
      float y = bf2f(yHi[e]) + bf2f(yLo[e]);
      float cz = (mode == 2) ? 0.25f : 0.5f;
      float z = fmaf(cz, kv, y);
      accBuf[e] = fmaf(1.0f / 6.0f, kv, accBuf[e]);
      unsigned short hi = f2bf(z);
      outHi[e] = hi;
      outLo[e] = f2bf(z - bf2f(hi));
    } else {                                  // k4: ynew = ACC + k/12
      float z = fmaf(1.0f / 12.0f, kv, accBuf[e]);
      unsigned short hi = f2bf(z);
      outHi[e] = hi;
      outLo[e] = f2bf(z - bf2f(hi));
      if (outsPtr) outsPtr[e] = z;
    }
  }
}

// ---------------- persistent ODE kernel: all 288 convs, region-sync ------------
// grid 256 = 4 ocg x 4 batch x 16 row-pairs (bid = g*64 + b*16 + rp).
// rpdone[b*16+rp]: total convs completed by that region's 4 oc-blocks (release).
// Before conv #done, block waits rpdone[rp-1,rp,rp+1] >= 4*done (acquire): all
// producers of its halo + its own region's other channels finished conv done-1.
// Skew bound: interacting blocks co-execute only the SAME conv index; write
// buffer != read buffer for every conv (S->T0->T1->T0->S) => no RAW/WAR.
// 1 block/CU (2/CU capacity at 79KB LDS) => all 256 co-resident, deadlock-free.
__global__ __launch_bounds__(256) void ode_persist(
    const unsigned short* __restrict__ wimg,
    const float* __restrict__ b1, const float* __restrict__ b2,
    const float* __restrict__ b3, const float* __restrict__ b4,
    unsigned short* __restrict__ S0h, unsigned short* __restrict__ S0l,
    unsigned short* __restrict__ S1h, unsigned short* __restrict__ S1l,
    unsigned short* __restrict__ T0h, unsigned short* __restrict__ T0l,
    unsigned short* __restrict__ T1h, unsigned short* __restrict__ T1l,
    float* __restrict__ accBuf, float* __restrict__ outs, int* rpdone) {
  extern __shared__ uint8_t lds[];
  const int bid = blockIdx.x;
  const int g = bid >> 6;
  const int b = (bid >> 4) & 3;
  const int rp = bid & 15;
  const int h0 = rp << 1;

  const unsigned short* Wl[4] = {wimg, wimg + 73728, wimg + 147456, wimg + 221184};
  const float* Bl[4] = {b1, b2, b3, b4};

  int done = 0;
  for (int step = 1; step <= 18; ++step) {
    for (int sub = 0; sub < 4; ++sub) {
      for (int layer = 0; layer < 4; ++layer) {
        const unsigned short *iH, *iL;
        unsigned short *oH, *oL;
        int mode;
        float* op = nullptr;
        if (layer == 0) {
          iH = (sub == 0) ? S0h : S1h; iL = (sub == 0) ? S0l : S1l;
          oH = T0h; oL = T0l; mode = 0;
        } else if (layer == 1) {
          iH = T0h; iL = T0l; oH = T1h; oL = T1l; mode = 0;
        } else if (layer == 2) {
          iH = T1h; iL = T1l; oH = T0h; oL = T0l; mode = 0;
        } else {
          iH = T0h; iL = T0l;
          oH = (sub == 3) ? S0h : S1h; oL = (sub == 3) ? S0l : S1l;
          mode = 1 + sub;
          if (sub == 3 && (step & 1) == 0) op = outs + (size_t)(step >> 1) * 262144;
        }
        // ---- wait: halo producers + own region at >= done convs (acquire)
        if (threadIdx.x == 0 && done > 0) {
          const int need = 4 * done;
          const int base = b * 16;
#pragma unroll
          for (int drp = -1; drp <= 1; ++drp) {
            int q = rp + drp;
            if (q < 0 || q > 15) continue;
            while (__hip_atomic_load(&rpdone[base + q], __ATOMIC_ACQUIRE,
                                     __HIP_MEMORY_SCOPE_AGENT) < need)
              __builtin_amdgcn_s_sleep(2);
          }
          __threadfence();                    // extra acquire: drop stale L2
        }
        __syncthreads();

        conv_body(lds, b, h0, g, iH, iL, Wl[layer], Bl[layer], oH, oL,
                  S0h, S0l, accBuf, op, mode);

        __syncthreads();                      // all stores issued block-wide
        ++done;
        if (threadIdx.x == 0) {
          __threadfence();                    // release: publish conv outputs
          __hip_atomic_fetch_add(&rpdone[b * 16 + rp], 1, __ATOMIC_RELEASE,
                                 __HIP_MEMORY_SCOPE_AGENT);
        }
      }
    }
  }
}

// ---------------- decoder (fp32, thread-per-output) ----------------
__global__ void dec_s1(const float* __restrict__ in, const float* __restrict__ wt,
                       const float* __restrict__ bs, float* __restrict__ out) {
  int t = blockIdx.x * 256 + threadIdx.x;
  int oc = t & 31, ox = (t >> 5) & 63, oy = (t >> 11) & 63, n = t >> 17;
  float a = bs[oc];
#pragma unroll
  for (int ky = 0; ky < 4; ++ky) {
    int iy2 = oy + ky - 2;
    if (iy2 < 0 || (iy2 & 1)) continue;
    int iy = iy2 >> 1;
    if (iy >= 32) continue;
#pragma unroll
    for (int kx = 0; kx < 4; ++kx) {
      int ix2 = ox + kx - 2;
      if (ix2 < 0 || (ix2 & 1)) continue;
      int ix = ix2 >> 1;
      if (ix >= 32) continue;
      const float* xp = in + ((n * 32 + iy) * 32 + ix) * 64;
      const float* wp = wt + (ky * 4 + kx) * 2048 + oc;
#pragma unroll
      for (int ic = 0; ic < 64; ++ic) a = fmaf(xp[ic], wp[ic * 32], a);
    }
  }
  out[t] = (a > 0.f) ? a : 0.2f * a;
}

__global__ void dec_s2(const float* __restrict__ in, const float* __restrict__ wt,
                       const float* __restrict__ bs, float* __restrict__ out) {
  int t = blockIdx.x * 256 + threadIdx.x;
  int oc = t & 15, ox = (t >> 4) & 127, oy = (t >> 11) & 127, n = t >> 18;
  float a = bs[oc];
#pragma unroll
  for (int ky = 0; ky < 4; ++ky) {
    int iy2 = oy + ky - 2;
    if (iy2 < 0 || (iy2 & 1)) continue;
    int iy = iy2 >> 1;
    if (iy >= 64) continue;
#pragma unroll
    for (int kx = 0; kx < 4; ++kx) {
      int ix2 = ox + kx - 2;
      if (ix2 < 0 || (ix2 & 1)) continue;
      int ix = ix2 >> 1;
      if (ix >= 64) continue;
      const float* xp = in + ((n * 64 + iy) * 64 + ix) * 32;
      const float* wp = wt + (ky * 4 + kx) * 512 + oc;
#pragma unroll
      for (int ic = 0; ic < 32; ++ic) a = fmaf(xp[ic], wp[ic * 16], a);
    }
  }
  out[t] = (a > 0.f) ? a : 0.2f * a;
}

__global__ void dec_s3(const float* __restrict__ in, const float* __restrict__ wt,
                       const float* __restrict__ bs, float* __restrict__ out) {
  int t = blockIdx.x * 256 + threadIdx.x;
  int ox = t & 127, oy = (t >> 7) & 127, n = t >> 14;
  float a = bs[0];
#pragma unroll
  for (int ky = 0; ky < 3; ++ky) {
    int iy = oy + ky - 1;
    if (iy < 0 || iy >= 128) continue;
#pragma unroll
    for (int kx = 0; kx < 3; ++kx) {
      int ix = ox + kx - 1;
      if (ix < 0 || ix >= 128) continue;
      const float* xp = in + ((n * 128 + iy) * 128 + ix) * 16;
      const float* wp = wt + (ky * 3 + kx) * 16;
#pragma unroll
      for (int ic = 0; ic < 16; ++ic) a = fmaf(xp[ic], wp[ic], a);
    }
  }
  out[n * 16384 + oy * 128 + ox] = a;
}

// ---------------- host ----------------
extern "C" void kernel_launch(void* const* d_in, const int* in_sizes, int n_in,
                              void* d_out, int out_size, void* d_ws, size_t ws_size,
                              hipStream_t stream) {
  (void)in_sizes; (void)n_in; (void)out_size;
  (void)hipFuncSetAttribute((const void*)ode_persist,
                            hipFuncAttributeMaxDynamicSharedMemorySize, CONV_LDS);

  uint8_t* ws = (uint8_t*)d_ws;
  unsigned short* S0h = (unsigned short*)(ws + 0);
  unsigned short* S0l = (unsigned short*)(ws + 524288);
  unsigned short* S1h = (unsigned short*)(ws + 1048576);
  unsigned short* S1l = (unsigned short*)(ws + 1572864);
  unsigned short* T0h = (unsigned short*)(ws + 2097152);
  unsigned short* T0l = (unsigned short*)(ws + 2621440);
  unsigned short* T1h = (unsigned short*)(ws + 3145728);
  unsigned short* T1l = (unsigned short*)(ws + 3670016);
  float* ACC = (float*)(ws + 4194304);
  unsigned short* WIMG = (unsigned short*)(ws + 5242880);
  float* s1wt = (float*)(ws + 5832704);
  float* s2wt = (float*)(ws + 5963776);
  float* s3wt = (float*)(ws + 5996544);
  int* rpdone = (int*)(ws + 6029312);         // 64 x int
  float* outs = (float*)(ws + 6291456);       // 10 x 262144 f32
  const size_t decBase = 16777216;

  const float* h_s0 = (const float*)d_in[0];
  const float* wode[4] = {(const float*)d_in[1], (const float*)d_in[3],
                          (const float*)d_in[5], (const float*)d_in[7]};
  const float* bode[4] = {(const float*)d_in[2], (const float*)d_in[4],
                          (const float*)d_in[6], (const float*)d_in[8]};
  const float* s1w = (const float*)d_in[9];
  const float* s1b = (const float*)d_in[10];
  const float* s2w = (const float*)d_in[11];
  const float* s2b = (const float*)d_in[12];
  const float* s3w = (const float*)d_in[13];
  const float* s3b = (const float*)d_in[14];

  (void)hipMemsetAsync(rpdone, 0, 64 * sizeof(int), stream);
  prep_weights<<<737, 256, 0, stream>>>(wode[0], wode[1], wode[2], wode[3],
                                        s1w, s2w, s3w, WIMG, s1wt, s2wt, s3wt);
  prep_state<<<1024, 256, 0, stream>>>(h_s0, S0h, S0l, outs);

  ode_persist<<<dim3(256), dim3(256), CONV_LDS, stream>>>(
      WIMG, bode[0], bode[1], bode[2], bode[3],
      S0h, S0l, S1h, S1l, T0h, T0l, T1h, T1l, ACC, outs, rpdone);

  // decoder, chunked over timesteps to fit workspace
  size_t avail = (ws_size > decBase) ? (ws_size - decBase) : 0;
  int TCc = (int)(avail / 6291456ull);
  if (TCc < 1) TCc = 1;
  if (TCc > 10) TCc = 10;
  for (int t0 = 0; t0 < 10; t0 += TCc) {
    int tc = (TCc < 10 - t0) ? TCc : (10 - t0);
    int n = tc * 4;
    float* d1 = (float*)(ws + decBase);
    float* d2 = d1 + (size_t)n * 131072;      // n*64*64*32
    dec_s1<<<n * 512, 256, 0, stream>>>(outs + (size_t)t0 * 262144, s1wt, s1b, d1);
    dec_s2<<<n * 1024, 256, 0, stream>>>(d1, s2wt, s2b, d2);
    dec_s3<<<n * 64, 256, 0, stream>>>(d2, s3wt, s3b,
                                       (float*)d_out + (size_t)t0 * 65536);
  }
}

// Round 7
// 4964.529 us; speedup vs baseline: 2.0920x; 2.0920x over previous
//
#include <hip/hip_runtime.h>
#include <hip/hip_bf16.h>
#include <stdint.h>

typedef __attribute__((ext_vector_type(8))) short short8;
typedef __attribute__((ext_vector_type(4))) float f32x4;
typedef __attribute__((ext_vector_type(4))) int int4v;

__device__ __forceinline__ float bf2f(unsigned short u) {
  union { unsigned int i; float f; } v; v.i = ((unsigned int)u) << 16; return v.f;
}
__device__ __forceinline__ unsigned short f2bf(float f) {
  union { float f; unsigned int i; } v; v.f = f;
  unsigned int i = v.i;
  i += 0x7FFFu + ((i >> 16) & 1u);
  return (unsigned short)(i >> 16);
}
__device__ __forceinline__ float tanh_fast(float x) {
  float e = __expf(2.0f * x);
  return 1.0f - 2.0f / (e + 1.0f);
}

// ---------------- weight prep ----------------
__global__ void prep_weights(const float* __restrict__ w1, const float* __restrict__ w2,
                             const float* __restrict__ w3, const float* __restrict__ w4,
                             const float* __restrict__ s1w, const float* __restrict__ s2w,
                             const float* __restrict__ s3w,
                             unsigned short* __restrict__ wimg,
                             float* __restrict__ s1wt, float* __restrict__ s2wt,
                             float* __restrict__ s3wt) {
  int t = blockIdx.x * 256 + threadIdx.x;
  if (t < 147456) {
    int l = t / 36864;
    int oc = (t / 576) & 63;
    int ic = (t / 9) & 63;
    int tap = t % 9;
    const float* w = (l == 0) ? w1 : (l == 1) ? w2 : (l == 2) ? w3 : w4;
    float v = w[(oc * 64 + ic) * 9 + tap];
    unsigned short hi = f2bf(v);
    unsigned short lo = f2bf(v - bf2f(hi));
    int icb = ic >> 5, icm = ic & 31;
    int idx = (icb * 64 + oc) * 288 + tap * 32 + icm;
    wimg[l * 73728 + idx]         = hi;
    wimg[l * 73728 + 36864 + idx] = lo;
  } else if (t < 180224) {
    int u = t - 147456;                       // ((ky*4+kx)*64+ic)*32+oc
    int oc = u & 31, ic = (u >> 5) & 63, kk = u >> 11;
    int ky = kk >> 2, kx = kk & 3;
    s1wt[u] = s1w[((oc * 64 + ic) * 4 + ky) * 4 + kx];
  } else if (t < 188416) {
    int u = t - 180224;                       // ((ky*4+kx)*32+ic)*16+oc
    int oc = u & 15, ic = (u >> 4) & 31, kk = u >> 9;
    int ky = kk >> 2, kx = kk & 3;
    s2wt[u] = s2w[((oc * 32 + ic) * 4 + ky) * 4 + kx];
  } else if (t < 188560) {
    int u = t - 188416;                       // (ky*3+kx)*16+ic
    int ic = u & 15, kk = u >> 4;
    int ky = kk / 3, kx = kk % 3;
    s3wt[u] = s3w[ic * 9 + ky * 3 + kx];
  }
}

// NCHW h_s0 -> NHWC bf16 pair (S0) + f32 outs[0]
__global__ void prep_state(const float* __restrict__ src,
                           unsigned short* __restrict__ s0h, unsigned short* __restrict__ s0l,
                           float* __restrict__ outs0) {
  int t = blockIdx.x * 256 + threadIdx.x;    // NHWC flat: ((b*32+h)*32+w)*64+c
  int c = t & 63, w = (t >> 6) & 31, h = (t >> 11) & 31, b = t >> 16;
  float v = src[((b * 64 + c) * 32 + h) * 32 + w];
  unsigned short hi = f2bf(v);
  s0h[t] = hi;
  s0l[t] = f2bf(v - bf2f(hi));
  outs0[t] = v;
}

// ---------------- ODE conv body (1024 thr, 16 waves; wave = M16 x N16) --------
// LDS: A [arr2][row4][w34][144B] = 39168 B ; W (one icb) [arr2][oc64][624B] = 79872 B
#define LDS_A_ARR 19584
#define LDS_W_BASE 39168
#define LDS_W_ARR 39936
#define CONV_LDS 119040

__device__ __forceinline__ void conv_body(
    uint8_t* lds, int b, int h0,
    const unsigned short* __restrict__ inHi, const unsigned short* __restrict__ inLo,
    const unsigned short* __restrict__ wimg, const float* __restrict__ bias,
    unsigned short* __restrict__ outHi, unsigned short* __restrict__ outLo,
    float* Y, float* R, float* __restrict__ outsPtr, int mode) {
  const int tid = threadIdx.x;

  // ---- stage A-tile (rows h0-1..h0+2, w 0..33 padded, 8x16B ic-chunks, hi+lo)
  for (int idx = tid; idx < 2176; idx += 1024) {
    int arr = idx / 1088;
    int r2 = idx - arr * 1088;
    int c = r2 & 7;
    int w1 = (r2 >> 3) % 34;
    int row = (r2 >> 3) / 34;
    int hp = h0 - 1 + row;
    int w = w1 - 1;
    int4v v = {0, 0, 0, 0};
    if (hp >= 0 && hp < 32 && w >= 0 && w < 32) {
      const unsigned short* sp = arr ? inLo : inHi;
      v = *(const int4v*)(sp + (((b * 32 + hp) * 32 + w) * 64 + c * 8));
    }
    *(int4v*)(lds + ((arr * 4 + row) * 34 + w1) * 144 + c * 16) = v;
  }
  // ---- stage W icb=0 ; prefetch icb=1 into regs (write after phase-0 compute)
  int4v wpre[5];
#pragma unroll
  for (int k = 0; k < 5; ++k) {
    int idx = tid + k * 1024;                 // 0..4607
    if (idx < 4608) {
      int arr = idx / 2304;
      int r2 = idx - arr * 2304;
      int oc = r2 / 36;
      int ch = r2 - oc * 36;
      int4v v0 = *(const int4v*)(wimg + (((arr * 2 + 0) * 64 + oc) * 288 + ch * 8));
      *(int4v*)(lds + LDS_W_BASE + (arr * 64 + oc) * 624 + ch * 16) = v0;
      wpre[k] = *(const int4v*)(wimg + (((arr * 2 + 1) * 64 + oc) * 288 + ch * 8));
    }
  }
  __syncthreads();

  const int lane = tid & 63;
  const int wv = tid >> 6;                    // 0..15
  const int mq = wv & 3;                      // M16 quarter
  const int ng = wv >> 2;                     // N16 group
  const int lmod = lane & 15;
  const int lg = lane >> 4;
  const int P = mq * 16 + lmod;               // A pixel (m = lane&15)
  const int r = P >> 5;
  const int c0 = P & 31;

  f32x4 acc = (f32x4){0.f, 0.f, 0.f, 0.f};

#pragma unroll
  for (int icb = 0; icb < 2; ++icb) {
    if (icb == 1) {
      __syncthreads();
#pragma unroll
      for (int k = 0; k < 5; ++k) {
        int idx = tid + k * 1024;
        if (idx < 4608) {
          int arr = idx / 2304;
          int r2 = idx - arr * 2304;
          int oc = r2 / 36;
          int ch = r2 - oc * 36;
          *(int4v*)(lds + LDS_W_BASE + (arr * 64 + oc) * 624 + ch * 16) = wpre[k];
        }
      }
      __syncthreads();
    }
#pragma unroll
    for (int tap = 0; tap < 9; ++tap) {
      const int dy = tap / 3, dx = tap % 3;
      const int abyte = ((r + dy) * 34 + (c0 + dx)) * 144 + (icb * 4 + lg) * 16;
      short8 ah = *(const short8*)(lds + abyte);
      short8 al = *(const short8*)(lds + abyte + LDS_A_ARR);
      const int wb = LDS_W_BASE + (ng * 16 + lmod) * 624 + tap * 64 + lg * 16;
      short8 bh = *(const short8*)(lds + wb);
      short8 bl = *(const short8*)(lds + wb + LDS_W_ARR);
      acc = __builtin_amdgcn_mfma_f32_16x16x32_bf16(ah, bh, acc, 0, 0, 0);
      acc = __builtin_amdgcn_mfma_f32_16x16x32_bf16(al, bh, acc, 0, 0, 0);
      acc = __builtin_amdgcn_mfma_f32_16x16x32_bf16(ah, bl, acc, 0, 0, 0);
    }
  }

  // ---- epilogue: D[m=(lane>>4)*4+j][n=lane&15]; oc = ng*16+n, px = mq*16+m
  const int oc = ng * 16 + lmod;
  const float bz = bias[oc];
#pragma unroll
  for (int j = 0; j < 4; ++j) {
    const int Pp = mq * 16 + lg * 4 + j;
    const int e = (b * 1024 + h0 * 32 + Pp) * 64 + oc;
    float kv = acc[j] + bz;
    if (mode == 0) {                          // conv + tanh -> pair
      float v = tanh_fast(kv);
      unsigned short hi = f2bf(v);
      outHi[e] = hi;
      outLo[e] = f2bf(v - bf2f(hi));
    } else if (mode == 1) {                   // k1: z=y+0.25k ; R=y+k/12
      float z = fmaf(0.25f, kv, Y[j]);
      R[j] = fmaf(1.0f / 12.0f, kv, Y[j]);
      unsigned short hi = f2bf(z);
      outHi[e] = hi;
      outLo[e] = f2bf(z - bf2f(hi));
    } else if (mode == 2 || mode == 3) {      // k2/k3
      float cz = (mode == 2) ? 0.25f : 0.5f;
      float z = fmaf(cz, kv, Y[j]);
      R[j] = fmaf(1.0f / 6.0f, kv, R[j]);
      unsigned short hi = f2bf(z);
      outHi[e] = hi;
      outLo[e] = f2bf(z - bf2f(hi));
    } else {                                  // k4: ynew = R + k/12
      float z = fmaf(1.0f / 12.0f, kv, R[j]);
      Y[j] = z;
      unsigned short hi = f2bf(z);
      outHi[e] = hi;
      outLo[e] = f2bf(z - bf2f(hi));
      if (outsPtr) outsPtr[e] = z;
    }
  }
}

// ---------------- persistent ODE kernel: 64 blocks x 16 waves, neighbor-sync ---
// grid 64 = 4 batch x 16 row-pairs; 1 block/CU (LDS 119K), 4 waves/SIMD TLP.
// progress[blk] = convs completed (release). Conv j needs neighbors >= j (acquire).
// Write buffer != read buffer each conv (S->T0->T1->T0->S) => skew<=1 is safe.
__global__ __launch_bounds__(1024) void ode_persist(
    const unsigned short* __restrict__ wimg,
    const float* __restrict__ b1, const float* __restrict__ b2,
    const float* __restrict__ b3, const float* __restrict__ b4,
    unsigned short* __restrict__ S0h, unsigned short* __restrict__ S0l,
    unsigned short* __restrict__ S1h, unsigned short* __restrict__ S1l,
    unsigned short* __restrict__ T0h, unsigned short* __restrict__ T0l,
    unsigned short* __restrict__ T1h, unsigned short* __restrict__ T1l,
    float* __restrict__ outs, int* progress) {
  extern __shared__ uint8_t lds[];
  const int blk = blockIdx.x;
  const int b = blk >> 4;
  const int rp = blk & 15;
  const int h0 = rp << 1;
  const int nbA = (rp > 0) ? blk - 1 : -1;
  const int nbB = (rp < 15) ? blk + 1 : -1;

  const unsigned short* Wl[4] = {wimg, wimg + 73728, wimg + 147456, wimg + 221184};
  const float* Bl[4] = {b1, b2, b3, b4};

  // per-thread RK4 state: 4 outputs at (px = mq*16+lg*4+j, oc = ng*16+lmod)
  const int lane = threadIdx.x & 63;
  const int wv = threadIdx.x >> 6;
  const int mq = wv & 3, ng = wv >> 2;
  const int lmod = lane & 15, lg = lane >> 4;
  float Y[4], R[4];
#pragma unroll
  for (int j = 0; j < 4; ++j) {
    const int e = (b * 1024 + h0 * 32 + mq * 16 + lg * 4 + j) * 64 + ng * 16 + lmod;
    Y[j] = outs[e];                           // exact f32 initial state
    R[j] = 0.f;
  }

  int done = 0;
  for (int step = 1; step <= 18; ++step) {
    for (int sub = 0; sub < 4; ++sub) {
      for (int layer = 0; layer < 4; ++layer) {
        const unsigned short *iH, *iL;
        unsigned short *oH, *oL;
        int mode;
        float* op = nullptr;
        if (layer == 0) {
          iH = (sub == 0) ? S0h : S1h; iL = (sub == 0) ? S0l : S1l;
          oH = T0h; oL = T0l; mode = 0;
        } else if (layer == 1) {
          iH = T0h; iL = T0l; oH = T1h; oL = T1l; mode = 0;
        } else if (layer == 2) {
          iH = T1h; iL = T1l; oH = T0h; oL = T0l; mode = 0;
        } else {
          iH = T0h; iL = T0l;
          oH = (sub == 3) ? S0h : S1h; oL = (sub == 3) ? S0l : S1l;
          mode = 1 + sub;
          if (sub == 3 && (step & 1) == 0) op = outs + (size_t)(step >> 1) * 262144;
        }
        if (threadIdx.x == 0 && done > 0) {
          if (nbA >= 0)
            while (__hip_atomic_load(&progress[nbA], __ATOMIC_ACQUIRE,
                                     __HIP_MEMORY_SCOPE_AGENT) < done)
              __builtin_amdgcn_s_sleep(2);
          if (nbB >= 0)
            while (__hip_atomic_load(&progress[nbB], __ATOMIC_ACQUIRE,
                                     __HIP_MEMORY_SCOPE_AGENT) < done)
              __builtin_amdgcn_s_sleep(2);
          __threadfence();
        }
        __syncthreads();

        conv_body(lds, b, h0, iH, iL, Wl[layer], Bl[layer], oH, oL,
                  Y, R, op, mode);

        __syncthreads();
        ++done;
        if (threadIdx.x == 0) {
          __threadfence();
          __hip_atomic_store(&progress[blk], done, __ATOMIC_RELEASE,
                             __HIP_MEMORY_SCOPE_AGENT);
        }
      }
    }
  }
}

// ---------------- decoder (fp32, thread-per-output) ----------------
__global__ void dec_s1(const float* __restrict__ in, const float* __restrict__ wt,
                       const float* __restrict__ bs, float* __restrict__ out) {
  int t = blockIdx.x * 256 + threadIdx.x;
  int oc = t & 31, ox = (t >> 5) & 63, oy = (t >> 11) & 63, n = t >> 17;
  float a = bs[oc];
#pragma unroll
  for (int ky = 0; ky < 4; ++ky) {
    int iy2 = oy + ky - 2;
    if (iy2 < 0 || (iy2 & 1)) continue;
    int iy = iy2 >> 1;
    if (iy >= 32) continue;
#pragma unroll
    for (int kx = 0; kx < 4; ++kx) {
      int ix2 = ox + kx - 2;
      if (ix2 < 0 || (ix2 & 1)) continue;
      int ix = ix2 >> 1;
      if (ix >= 32) continue;
      const float* xp = in + ((n * 32 + iy) * 32 + ix) * 64;
      const float* wp = wt + (ky * 4 + kx) * 2048 + oc;
#pragma unroll
      for (int ic = 0; ic < 64; ++ic) a = fmaf(xp[ic], wp[ic * 32], a);
    }
  }
  out[t] = (a > 0.f) ? a : 0.2f * a;
}

__global__ void dec_s2(const float* __restrict__ in, const float* __restrict__ wt,
                       const float* __restrict__ bs, float* __restrict__ out) {
  int t = blockIdx.x * 256 + threadIdx.x;
  int oc = t & 15, ox = (t >> 4) & 127, oy = (t >> 11) & 127, n = t >> 18;
  float a = bs[oc];
#pragma unroll
  for (int ky = 0; ky < 4; ++ky) {
    int iy2 = oy + ky - 2;
    if (iy2 < 0 || (iy2 & 1)) continue;
    int iy = iy2 >> 1;
    if (iy >= 64) continue;
#pragma unroll
    for (int kx = 0; kx < 4; ++kx) {
      int ix2 = ox + kx - 2;
      if (ix2 < 0 || (ix2 & 1)) continue;
      int ix = ix2 >> 1;
      if (ix >= 64) continue;
      const float* xp = in + ((n * 64 + iy) * 64 + ix) * 32;
      const float* wp = wt + (ky * 4 + kx) * 512 + oc;
#pragma unroll
      for (int ic = 0; ic < 32; ++ic) a = fmaf(xp[ic], wp[ic * 16], a);
    }
  }
  out[t] = (a > 0.f) ? a : 0.2f * a;
}

__global__ void dec_s3(const float* __restrict__ in, const float* __restrict__ wt,
                       const float* __restrict__ bs, float* __restrict__ out) {
  int t = blockIdx.x * 256 + threadIdx.x;
  int ox = t & 127, oy = (t >> 7) & 127, n = t >> 14;
  float a = bs[0];
#pragma unroll
  for (int ky = 0; ky < 3; ++ky) {
    int iy = oy + ky - 1;
    if (iy < 0 || iy >= 128) continue;
#pragma unroll
    for (int kx = 0; kx < 3; ++kx) {
      int ix = ox + kx - 1;
      if (ix < 0 || ix >= 128) continue;
      const float* xp = in + ((n * 128 + iy) * 128 + ix) * 16;
      const float* wp = wt + (ky * 3 + kx) * 16;
#pragma unroll
      for (int ic = 0; ic < 16; ++ic) a = fmaf(xp[ic], wp[ic], a);
    }
  }
  out[n * 16384 + oy * 128 + ox] = a;
}

// ---------------- host ----------------
extern "C" void kernel_launch(void* const* d_in, const int* in_sizes, int n_in,
                              void* d_out, int out_size, void* d_ws, size_t ws_size,
                              hipStream_t stream) {
  (void)in_sizes; (void)n_in; (void)out_size;
  (void)hipFuncSetAttribute((const void*)ode_persist,
                            hipFuncAttributeMaxDynamicSharedMemorySize, CONV_LDS);

  uint8_t* ws = (uint8_t*)d_ws;
  unsigned short* S0h = (unsigned short*)(ws + 0);
  unsigned short* S0l = (unsigned short*)(ws + 524288);
  unsigned short* S1h = (unsigned short*)(ws + 1048576);
  unsigned short* S1l = (unsigned short*)(ws + 1572864);
  unsigned short* T0h = (unsigned short*)(ws + 2097152);
  unsigned short* T0l = (unsigned short*)(ws + 2621440);
  unsigned short* T1h = (unsigned short*)(ws + 3145728);
  unsigned short* T1l = (unsigned short*)(ws + 3670016);
  unsigned short* WIMG = (unsigned short*)(ws + 5242880);
  float* s1wt = (float*)(ws + 5832704);
  float* s2wt = (float*)(ws + 5963776);
  float* s3wt = (float*)(ws + 5996544);
  int* progress = (int*)(ws + 6029312);       // 64 x int
  float* outs = (float*)(ws + 6291456);       // 10 x 262144 f32
  const size_t decBase = 16777216;

  const float* h_s0 = (const float*)d_in[0];
  const float* wode[4] = {(const float*)d_in[1], (const float*)d_in[3],
                          (const float*)d_in[5], (const float*)d_in[7]};
  const float* bode[4] = {(const float*)d_in[2], (const float*)d_in[4],
                          (const float*)d_in[6], (const float*)d_in[8]};
  const float* s1w = (const float*)d_in[9];
  const float* s1b = (const float*)d_in[10];
  const float* s2w = (const float*)d_in[11];
  const float* s2b = (const float*)d_in[12];
  const float* s3w = (const float*)d_in[13];
  const float* s3b = (const float*)d_in[14];

  (void)hipMemsetAsync(progress, 0, 64 * sizeof(int), stream);
  prep_weights<<<737, 256, 0, stream>>>(wode[0], wode[1], wode[2], wode[3],
                                        s1w, s2w, s3w, WIMG, s1wt, s2wt, s3wt);
  prep_state<<<1024, 256, 0, stream>>>(h_s0, S0h, S0l, outs);

  ode_persist<<<dim3(64), dim3(1024), CONV_LDS, stream>>>(
      WIMG, bode[0], bode[1], bode[2], bode[3],
      S0h, S0l, S1h, S1l, T0h, T0l, T1h, T1l, outs, progress);

  // decoder, chunked over timesteps to fit workspace
  size_t avail = (ws_size > decBase) ? (ws_size - decBase) : 0;
  int TCc = (int)(avail / 6291456ull);
  if (TCc < 1) TCc = 1;
  if (TCc > 10) TCc = 10;
  for (int t0 = 0; t0 < 10; t0 += TCc) {
    int tc = (TCc < 10 - t0) ? TCc : (10 - t0);
    int n = tc * 4;
    float* d1 = (float*)(ws + decBase);
    float* d2 = d1 + (size_t)n * 131072;      // n*64*64*32
    dec_s1<<<n * 512, 256, 0, stream>>>(outs + (size_t)t0 * 262144, s1wt, s1b, d1);
    dec_s2<<<n * 1024, 256, 0, stream>>>(d1, s2wt, s2b, d2);
    dec_s3<<<n * 64, 256, 0, stream>>>(d2, s3wt, s3b,
                                       (float*)d_out + (size_t)t0 * 65536);
  }
}